// Round 3
// baseline (233.158 us; speedup 1.0000x reference)
//
#include <hip/hip_runtime.h>
#include <math.h>

#define BB   512
#define NN   512
#define MM   128
#define CC   1024
#define ADDR 134
#define EPSF 1e-8f

__device__ __forceinline__ float softplus_f(float x) {
    return fmaxf(x, 0.0f) + log1pf(expf(-fabsf(x)));
}

// 16 waves/CU, 1 block/CU: VGPR cap 128 so the 16 float4 row-fragments stay in registers.
__global__ __launch_bounds__(1024, 4) void ntm_head_kernel(
    const float* __restrict__ co,      // B x C
    const float* __restrict__ prev_w,  // B x N
    const float* __restrict__ mem,     // B x N x M
    const float* __restrict__ W_fc,    // C x ADDR
    const float* __restrict__ b_fc,    // ADDR
    float* __restrict__ out_rv,        // B x M
    float* __restrict__ out_w)         // B x N
{
    __shared__ __align__(16) float s_co[CC];      // 4 KB
    __shared__ __align__(16) float s_k[MM];       // 512 B
    __shared__ float s_extra[8];
    __shared__ __align__(16) float s_bsim[NN];    // 2 KB (reused for pass-2 reduce)
    __shared__ float s_wg[NN];                    // 2 KB
    __shared__ float s_w[NN];                     // 2 KB
    __shared__ __align__(16) float s_part[32 * MM]; // 16 KB
    __shared__ float s_red[16];
    __shared__ float s_params[8];

    const int t = threadIdx.x;
    const int b = blockIdx.x;
    const int gi = t >> 5;   // 32 groups of 32 lanes; group owns rows gi, gi+32, ..., gi+480
    const int l  = t & 31;
    const float4* memb = (const float4*)(mem + (size_t)b * NN * MM);

    // ---- phase 0: stage controller_out row ----
    s_co[t] = co[(size_t)b * CC + t];
    float pw = (t < NN) ? prev_w[(size_t)b * NN + t] : 0.0f;
    __syncthreads();

    // ---- phase 1: fc (out = co @ W_fc + b_fc), 8 C-partials x 128 outputs ----
    {
        const int o    = t & (MM - 1);
        const int part = t >> 7;
        const float* Wp = W_fc + o;
        float a0 = 0.f, a1 = 0.f, a2 = 0.f, a3 = 0.f;
        const int c0 = part * (CC / 8);
        for (int c = c0; c < c0 + CC / 8; c += 4) {
            float4 cv = *(const float4*)(s_co + c);
            a0 = fmaf(cv.x, Wp[(size_t)(c + 0) * ADDR], a0);
            a1 = fmaf(cv.y, Wp[(size_t)(c + 1) * ADDR], a1);
            a2 = fmaf(cv.z, Wp[(size_t)(c + 2) * ADDR], a2);
            a3 = fmaf(cv.w, Wp[(size_t)(c + 3) * ADDR], a3);
        }
        s_part[part * MM + o] = (a0 + a1) + (a2 + a3);

        const int wv = t >> 6;
        if (wv < 6) {
            const int ll = t & 63;
            const int oe = MM + wv;
            const float* We = W_fc + oe;
            float e = 0.f;
            for (int c = ll; c < CC; c += 64)
                e = fmaf(s_co[c], We[(size_t)c * ADDR], e);
            #pragma unroll
            for (int off = 32; off >= 1; off >>= 1) e += __shfl_xor(e, off, 64);
            if (ll == 0) s_extra[wv] = e + b_fc[oe];
        }
    }

    // ---- load ALL 16 row-fragments into registers; anchor with q = sum(a^2) partials.
    // The q-computation is a real data dependence: the scheduler must issue these
    // loads here, and liveness keeps the data in VGPRs through pass 2 (no re-read).
    float4 p[16];
    float qq[16];
    #pragma unroll
    for (int jj = 0; jj < 16; ++jj) {
        p[jj] = memb[(size_t)gi * 32 + l + (size_t)jj * 1024];
        qq[jj] = p[jj].x * p[jj].x + p[jj].y * p[jj].y
               + p[jj].z * p[jj].z + p[jj].w * p[jj].w;
    }

    __syncthreads();

    // ---- phase 1b: reduce fc partials, ||k||, scalar params ----
    if (t < MM) {
        float r = b_fc[t];
        #pragma unroll
        for (int q = 0; q < 8; ++q) r += s_part[q * MM + t];
        s_k[t] = r;
        float v = r * r;
        #pragma unroll
        for (int off = 32; off >= 1; off >>= 1) v += __shfl_xor(v, off, 64);
        if ((t & 63) == 0) s_red[t >> 6] = v;
    }
    __syncthreads();
    if (t == 0) {
        float ks = s_red[0] + s_red[1];
        float norm_k = sqrtf(ks) + EPSF;
        float beta = softplus_f(s_extra[0]);
        float g = 1.0f / (1.0f + expf(-s_extra[1]));
        float e0 = s_extra[2], e1 = s_extra[3], e2 = s_extra[4];
        float mx = fmaxf(e0, fmaxf(e1, e2));
        float x0 = expf(e0 - mx), x1 = expf(e1 - mx), x2 = expf(e2 - mx);
        float inv = 1.0f / (x0 + x1 + x2);
        s_params[0] = beta / norm_k;
        s_params[1] = g;
        s_params[2] = x0 * inv;
        s_params[3] = x1 * inv;
        s_params[4] = x2 * inv;
        s_params[5] = 1.0f + softplus_f(s_extra[5]);
    }
    __syncthreads();

    const float bnk = s_params[0];
    const float4 kv = ((const float4*)s_k)[l];

    // ---- pass 1: beta * cosine sim; value-folding tree (17 shfl / 4 rows vs 40) ----
    #pragma unroll
    for (int j = 0; j < 16; j += 4) {
        float d0 = p[j  ].x*kv.x + p[j  ].y*kv.y + p[j  ].z*kv.z + p[j  ].w*kv.w;
        float d1 = p[j+1].x*kv.x + p[j+1].y*kv.y + p[j+1].z*kv.z + p[j+1].w*kv.w;
        float d2 = p[j+2].x*kv.x + p[j+2].y*kv.y + p[j+2].z*kv.z + p[j+2].w*kv.w;
        float d3 = p[j+3].x*kv.x + p[j+3].y*kv.y + p[j+3].z*kv.z + p[j+3].w*kv.w;
        float q0 = qq[j], q1 = qq[j+1], q2 = qq[j+2], q3 = qq[j+3];

        // L1: fold over lane^16, then pair d_i with q_i
        d0 += __shfl_xor(d0, 16, 64); q0 += __shfl_xor(q0, 16, 64);
        d1 += __shfl_xor(d1, 16, 64); q1 += __shfl_xor(q1, 16, 64);
        d2 += __shfl_xor(d2, 16, 64); q2 += __shfl_xor(q2, 16, 64);
        d3 += __shfl_xor(d3, 16, 64); q3 += __shfl_xor(q3, 16, 64);
        float W0 = (l & 16) ? q0 : d0;
        float W1 = (l & 16) ? q1 : d1;
        float W2 = (l & 16) ? q2 : d2;
        float W3 = (l & 16) ? q3 : d3;
        // L2: fold over lane^8, pair (W0,W1) and (W2,W3)
        W0 += __shfl_xor(W0, 8, 64); W1 += __shfl_xor(W1, 8, 64);
        W2 += __shfl_xor(W2, 8, 64); W3 += __shfl_xor(W3, 8, 64);
        float X0 = (l & 8) ? W1 : W0;
        float X1 = (l & 8) ? W3 : W2;
        // L3: fold over lane^4, pair (X0,X1)
        X0 += __shfl_xor(X0, 4, 64); X1 += __shfl_xor(X1, 4, 64);
        float Y = (l & 4) ? X1 : X0;
        // L4+L5: finish within 4-lane chunks
        Y += __shfl_xor(Y, 2, 64);
        Y += __shfl_xor(Y, 1, 64);
        // chunk layout: lanes 0-3:d(j+0) 4-7:d(j+2) 8-11:d(j+1) 12-15:d(j+3); +16: matching q
        float Q = __shfl_xor(Y, 16, 64);
        if (l < 16 && (l & 3) == 0) {
            int jj = j + ((l & 4) >> 1) + ((l & 8) >> 3);
            s_bsim[gi + jj * 32] = bnk * Y / (sqrtf(Q) + EPSF);
        }
    }
    __syncthreads();

    // ---- softmax -> gate -> shift -> sharpen -> normalize (threads 0-511) ----
    {
        const float NEG = -3.0e38f;
        float b1 = (t < NN) ? s_bsim[t] : NEG;

        float m = b1;
        #pragma unroll
        for (int off = 32; off >= 1; off >>= 1) m = fmaxf(m, __shfl_xor(m, off, 64));
        if ((t & 63) == 0) s_red[t >> 6] = m;
        __syncthreads();
        float M8 = s_red[0];
        #pragma unroll
        for (int i = 1; i < 8; ++i) M8 = fmaxf(M8, s_red[i]);
        __syncthreads();

        float e1 = (t < NN) ? expf(b1 - M8) : 0.0f;
        float ls = e1;
        #pragma unroll
        for (int off = 32; off >= 1; off >>= 1) ls += __shfl_xor(ls, off, 64);
        if ((t & 63) == 0) s_red[t >> 6] = ls;
        __syncthreads();
        float S = s_red[0];
        #pragma unroll
        for (int i = 1; i < 8; ++i) S += s_red[i];
        __syncthreads();

        const float invS = 1.0f / S;
        const float g = s_params[1];
        float wg1 = fmaf(g, e1 * invS, (1.0f - g) * pw);
        if (t < NN) s_wg[t] = wg1;
        __syncthreads();

        const float sh0 = s_params[2], sh1 = s_params[3], sh2 = s_params[4];
        const float gamma = s_params[5];
        float wp1 = 0.0f;
        if (t < NN) {
            float ws1 = sh0 * s_wg[(t + NN - 1) & (NN - 1)]
                      + sh1 * wg1
                      + sh2 * s_wg[(t + 1) & (NN - 1)];
            wp1 = powf(ws1, gamma);
        }
        float lz = wp1;
        #pragma unroll
        for (int off = 32; off >= 1; off >>= 1) lz += __shfl_xor(lz, off, 64);
        if ((t & 63) == 0) s_red[t >> 6] = lz;
        __syncthreads();
        float Z = s_red[0];
        #pragma unroll
        for (int i = 1; i < 8; ++i) Z += s_red[i];
        __syncthreads();

        const float invZ = 1.0f / (Z + EPSF);
        if (t < NN) {
            float w1 = wp1 * invZ;
            s_w[t] = w1;
            out_w[(size_t)b * NN + t] = w1;
        }
    }
    __syncthreads();

    // ---- pass 2: read_vec = w @ mem, ENTIRELY from registers (zero memory re-read) ----
    {
        float4 acc = make_float4(0.f, 0.f, 0.f, 0.f);
        #pragma unroll
        for (int jj = 0; jj < 16; ++jj) {
            float w = s_w[gi + jj * 32];   // 2 broadcast addrs per wave: conflict-free
            acc.x = fmaf(w, p[jj].x, acc.x);
            acc.y = fmaf(w, p[jj].y, acc.y);
            acc.z = fmaf(w, p[jj].z, acc.z);
            acc.w = fmaf(w, p[jj].w, acc.w);
        }
        *((float4*)&s_part[gi * MM + l * 4]) = acc;
        __syncthreads();

        if (t < 512) {
            const int h = t >> 7;
            const int o = t & (MM - 1);
            float r = 0.f;
            #pragma unroll
            for (int q = 0; q < 8; ++q) r += s_part[(h * 8 + q) * MM + o];
            s_bsim[h * MM + o] = r;
        }
        __syncthreads();
        if (t < MM) {
            float r = s_bsim[t] + s_bsim[MM + t] + s_bsim[2 * MM + t] + s_bsim[3 * MM + t];
            out_rv[(size_t)b * MM + t] = r;
        }
    }
}

extern "C" void kernel_launch(void* const* d_in, const int* in_sizes, int n_in,
                              void* d_out, int out_size, void* d_ws, size_t ws_size,
                              hipStream_t stream) {
    const float* co     = (const float*)d_in[0];
    const float* prev_w = (const float*)d_in[1];
    const float* mem    = (const float*)d_in[2];
    const float* W_fc   = (const float*)d_in[3];
    const float* b_fc   = (const float*)d_in[4];
    float* out = (float*)d_out;
    ntm_head_kernel<<<BB, 1024, 0, stream>>>(co, prev_w, mem, W_fc, b_fc,
                                             out, out + (size_t)BB * MM);
}

// Round 4
// 230.879 us; speedup vs baseline: 1.0099x; 1.0099x over previous
//
#include <hip/hip_runtime.h>
#include <math.h>

#define BB   512
#define NN   512
#define MM   128
#define CC   1024
#define ADDR 134
#define EPSF 1e-8f

#define KEEP(x) asm volatile("" : "+v"(x))

__device__ __forceinline__ float softplus_f(float x) {
    return fmaxf(x, 0.0f) + log1pf(expf(-fabsf(x)));
}

// 1 block/CU, 16 waves: VGPR cap 128 so the 16 float4 row-fragments stay in registers.
__global__ __launch_bounds__(1024, 4) void ntm_head_kernel(
    const float* __restrict__ co,      // B x C
    const float* __restrict__ prev_w,  // B x N
    const float* __restrict__ mem,     // B x N x M
    const float* __restrict__ W_fc,    // C x ADDR
    const float* __restrict__ b_fc,    // ADDR
    float* __restrict__ out_rv,        // B x M
    float* __restrict__ out_w)         // B x N
{
    __shared__ __align__(16) float s_co[CC];      // 4 KB
    __shared__ __align__(16) float s_k[MM];       // 512 B
    __shared__ float s_extra[8];
    __shared__ __align__(16) float s_bsim[NN];    // 2 KB (reused for pass-2 reduce)
    __shared__ float s_wg[NN];                    // 2 KB
    __shared__ float s_w[NN];                     // 2 KB (holds UNNORMALIZED wp)
    __shared__ __align__(16) float s_part[32 * MM]; // 16 KB
    __shared__ float s_red[16];
    __shared__ float s_params[8];

    const int t = threadIdx.x;
    const int b = blockIdx.x;
    const int gi = t >> 5;   // 32 groups of 32 lanes; group owns rows gi, gi+32, ..., gi+480
    const int l  = t & 31;
    const float4* memb = (const float4*)(mem + (size_t)b * NN * MM);

    // ---- phase 0: stage controller_out row ----
    s_co[t] = co[(size_t)b * CC + t];
    float pw = (t < NN) ? prev_w[(size_t)b * NN + t] : 0.0f;

    // ---- issue ALL 16 row-fragment loads NOW: HBM latency hides under the fc loop ----
    float4 p[16];
    #pragma unroll
    for (int jj = 0; jj < 16; ++jj)
        p[jj] = memb[(size_t)gi * 32 + l + (size_t)jj * 1024];

    __syncthreads();

    // ---- phase 1: fc (out = co @ W_fc + b_fc), 8 C-partials x 128 outputs ----
    {
        const int o    = t & (MM - 1);
        const int part = t >> 7;
        const float* Wp = W_fc + o;
        float a0 = 0.f, a1 = 0.f, a2 = 0.f, a3 = 0.f;
        const int c0 = part * (CC / 8);
        for (int c = c0; c < c0 + CC / 8; c += 4) {
            float4 cv = *(const float4*)(s_co + c);
            a0 = fmaf(cv.x, Wp[(size_t)(c + 0) * ADDR], a0);
            a1 = fmaf(cv.y, Wp[(size_t)(c + 1) * ADDR], a1);
            a2 = fmaf(cv.z, Wp[(size_t)(c + 2) * ADDR], a2);
            a3 = fmaf(cv.w, Wp[(size_t)(c + 3) * ADDR], a3);
        }
        s_part[part * MM + o] = (a0 + a1) + (a2 + a3);

        const int wv = t >> 6;
        if (wv < 6) {
            const int ll = t & 63;
            const int oe = MM + wv;
            const float* We = W_fc + oe;
            float e = 0.f;
            for (int c = ll; c < CC; c += 64)
                e = fmaf(s_co[c], We[(size_t)c * ADDR], e);
            #pragma unroll
            for (int off = 32; off >= 1; off >>= 1) e += __shfl_xor(e, off, 64);
            if (ll == 0) s_extra[wv] = e + b_fc[oe];
        }
    }

    // ---- anchor the row fragments: opaque to the compiler => cannot rematerialize,
    // must keep all 64 components resident in VGPRs through pass 2 (zero re-read).
    #pragma unroll
    for (int jj = 0; jj < 16; ++jj) {
        KEEP(p[jj].x); KEEP(p[jj].y); KEEP(p[jj].z); KEEP(p[jj].w);
    }

    __syncthreads();

    // ---- phase 1b: reduce fc partials, ||k||, scalar params ----
    if (t < MM) {
        float r = b_fc[t];
        #pragma unroll
        for (int q = 0; q < 8; ++q) r += s_part[q * MM + t];
        s_k[t] = r;
        float v = r * r;
        #pragma unroll
        for (int off = 32; off >= 1; off >>= 1) v += __shfl_xor(v, off, 64);
        if ((t & 63) == 0) s_red[t >> 6] = v;
    }
    __syncthreads();
    if (t == 0) {
        float ks = s_red[0] + s_red[1];
        float norm_k = sqrtf(ks) + EPSF;
        float beta = softplus_f(s_extra[0]);
        float g = 1.0f / (1.0f + expf(-s_extra[1]));
        float e0 = s_extra[2], e1 = s_extra[3], e2 = s_extra[4];
        float mx = fmaxf(e0, fmaxf(e1, e2));
        float x0 = expf(e0 - mx), x1 = expf(e1 - mx), x2 = expf(e2 - mx);
        float inv = 1.0f / (x0 + x1 + x2);
        s_params[0] = beta / norm_k;
        s_params[1] = g;
        s_params[2] = x0 * inv;
        s_params[3] = x1 * inv;
        s_params[4] = x2 * inv;
        s_params[5] = 1.0f + softplus_f(s_extra[5]);
    }
    __syncthreads();

    const float bnk = s_params[0];
    const float4 kv = ((const float4*)s_k)[l];

    // ---- pass 1: beta * cosine sim from registers; value-folding tree ----
    #pragma unroll
    for (int j = 0; j < 16; j += 4) {
        float d0 = p[j  ].x*kv.x + p[j  ].y*kv.y + p[j  ].z*kv.z + p[j  ].w*kv.w;
        float d1 = p[j+1].x*kv.x + p[j+1].y*kv.y + p[j+1].z*kv.z + p[j+1].w*kv.w;
        float d2 = p[j+2].x*kv.x + p[j+2].y*kv.y + p[j+2].z*kv.z + p[j+2].w*kv.w;
        float d3 = p[j+3].x*kv.x + p[j+3].y*kv.y + p[j+3].z*kv.z + p[j+3].w*kv.w;
        float q0 = p[j  ].x*p[j  ].x + p[j  ].y*p[j  ].y + p[j  ].z*p[j  ].z + p[j  ].w*p[j  ].w;
        float q1 = p[j+1].x*p[j+1].x + p[j+1].y*p[j+1].y + p[j+1].z*p[j+1].z + p[j+1].w*p[j+1].w;
        float q2 = p[j+2].x*p[j+2].x + p[j+2].y*p[j+2].y + p[j+2].z*p[j+2].z + p[j+2].w*p[j+2].w;
        float q3 = p[j+3].x*p[j+3].x + p[j+3].y*p[j+3].y + p[j+3].z*p[j+3].z + p[j+3].w*p[j+3].w;

        // L1: fold over lane^16, then pair d_i with q_i
        d0 += __shfl_xor(d0, 16, 64); q0 += __shfl_xor(q0, 16, 64);
        d1 += __shfl_xor(d1, 16, 64); q1 += __shfl_xor(q1, 16, 64);
        d2 += __shfl_xor(d2, 16, 64); q2 += __shfl_xor(q2, 16, 64);
        d3 += __shfl_xor(d3, 16, 64); q3 += __shfl_xor(q3, 16, 64);
        float W0 = (l & 16) ? q0 : d0;
        float W1 = (l & 16) ? q1 : d1;
        float W2 = (l & 16) ? q2 : d2;
        float W3 = (l & 16) ? q3 : d3;
        // L2: fold over lane^8, pair (W0,W1) and (W2,W3)
        W0 += __shfl_xor(W0, 8, 64); W1 += __shfl_xor(W1, 8, 64);
        W2 += __shfl_xor(W2, 8, 64); W3 += __shfl_xor(W3, 8, 64);
        float X0 = (l & 8) ? W1 : W0;
        float X1 = (l & 8) ? W3 : W2;
        // L3: fold over lane^4, pair (X0,X1)
        X0 += __shfl_xor(X0, 4, 64); X1 += __shfl_xor(X1, 4, 64);
        float Y = (l & 4) ? X1 : X0;
        // L4+L5: finish within 4-lane chunks
        Y += __shfl_xor(Y, 2, 64);
        Y += __shfl_xor(Y, 1, 64);
        // chunk layout: lanes 0-3:d(j+0) 4-7:d(j+2) 8-11:d(j+1) 12-15:d(j+3); +16: matching q
        float Q = __shfl_xor(Y, 16, 64);
        if (l < 16 && (l & 3) == 0) {
            int jj = j + ((l & 4) >> 1) + ((l & 8) >> 3);
            s_bsim[gi + jj * 32] = bnk * Y / (sqrtf(Q) + EPSF);
        }
    }
    __syncthreads();

    // ---- softmax -> gate -> shift -> sharpen (normalization deferred) ----
    float wp1 = 0.0f;
    {
        const float NEG = -3.0e38f;
        float b1 = (t < NN) ? s_bsim[t] : NEG;

        float m = b1;
        #pragma unroll
        for (int off = 32; off >= 1; off >>= 1) m = fmaxf(m, __shfl_xor(m, off, 64));
        if ((t & 63) == 0) s_red[t >> 6] = m;
        __syncthreads();
        float M8 = s_red[0];
        #pragma unroll
        for (int i = 1; i < 8; ++i) M8 = fmaxf(M8, s_red[i]);
        __syncthreads();

        float e1 = (t < NN) ? expf(b1 - M8) : 0.0f;
        float ls = e1;
        #pragma unroll
        for (int off = 32; off >= 1; off >>= 1) ls += __shfl_xor(ls, off, 64);
        if ((t & 63) == 0) s_red[t >> 6] = ls;
        __syncthreads();
        float S = s_red[0];
        #pragma unroll
        for (int i = 1; i < 8; ++i) S += s_red[i];
        __syncthreads();

        const float invS = 1.0f / S;
        const float g = s_params[1];
        float wg1 = fmaf(g, e1 * invS, (1.0f - g) * pw);
        if (t < NN) s_wg[t] = wg1;
        __syncthreads();

        const float sh0 = s_params[2], sh1 = s_params[3], sh2 = s_params[4];
        const float gamma = s_params[5];
        if (t < NN) {
            float ws1 = sh0 * s_wg[(t + NN - 1) & (NN - 1)]
                      + sh1 * wg1
                      + sh2 * s_wg[(t + 1) & (NN - 1)];
            wp1 = powf(ws1, gamma);
            s_w[t] = wp1;              // unnormalized; invZ applied at outputs
        }
    }
    __syncthreads();

    // ---- pass 2: read_unnorm = wp @ mem, ENTIRELY from registers; Z reduced alongside ----
    {
        float4 acc = make_float4(0.f, 0.f, 0.f, 0.f);
        #pragma unroll
        for (int jj = 0; jj < 16; ++jj) {
            float w = s_w[gi + jj * 32];   // 2 broadcast addrs per wave: conflict-free
            acc.x = fmaf(w, p[jj].x, acc.x);
            acc.y = fmaf(w, p[jj].y, acc.y);
            acc.z = fmaf(w, p[jj].z, acc.z);
            acc.w = fmaf(w, p[jj].w, acc.w);
        }

        // Z reduction (wp1 is 0 for t>=512, harmless)
        float lz = wp1;
        #pragma unroll
        for (int off = 32; off >= 1; off >>= 1) lz += __shfl_xor(lz, off, 64);
        if ((t & 63) == 0) s_red[t >> 6] = lz;

        *((float4*)&s_part[gi * MM + l * 4]) = acc;
        __syncthreads();

        float Z = s_red[0];
        #pragma unroll
        for (int i = 1; i < 8; ++i) Z += s_red[i];
        const float invZ = 1.0f / (Z + EPSF);

        if (t < NN) out_w[(size_t)b * NN + t] = wp1 * invZ;

        if (t < 512) {
            const int h = t >> 7;
            const int o = t & (MM - 1);
            float r = 0.f;
            #pragma unroll
            for (int q = 0; q < 8; ++q) r += s_part[(h * 8 + q) * MM + o];
            s_bsim[h * MM + o] = r;
        }
        __syncthreads();
        if (t < MM) {
            float r = s_bsim[t] + s_bsim[MM + t] + s_bsim[2 * MM + t] + s_bsim[3 * MM + t];
            out_rv[(size_t)b * MM + t] = r * invZ;
        }
    }
}

extern "C" void kernel_launch(void* const* d_in, const int* in_sizes, int n_in,
                              void* d_out, int out_size, void* d_ws, size_t ws_size,
                              hipStream_t stream) {
    const float* co     = (const float*)d_in[0];
    const float* prev_w = (const float*)d_in[1];
    const float* mem    = (const float*)d_in[2];
    const float* W_fc   = (const float*)d_in[3];
    const float* b_fc   = (const float*)d_in[4];
    float* out = (float*)d_out;
    ntm_head_kernel<<<BB, 1024, 0, stream>>>(co, prev_w, mem, W_fc, b_fc,
                                             out, out + (size_t)BB * MM);
}